// Round 7
// baseline (385.864 us; speedup 1.0000x reference)
//
#include <hip/hip_runtime.h>

// HGIN_classifier: two relational-GIN layers (R=2), ReLU between.
// R7: gemm rewritten barrier-free. R6's dbuf+register-prefetch spilled
// (VGPR cap 128 from launch_bounds(256,2) + 128 AGPR acc -> WRITE_SIZE 57MB).
// New gemm: no LDS staging at all — A frags loaded direct from global
// (wave touches 16 rows x 64B = full lines), B (192KB, L2-resident) direct.
// Wave = 64 rows x 64 cols (acc=64), block = 4 waves = 64 rows x 256 cols.
// Fully-unrolled K-loop, zero barriers until the zbuf epilogue.
// Pipeline: zero_small -> bucketA -> bscan -> bucketB -> bucketC (CSR build)
//           cvt_x, cvt_w -> aggregate (f16 gather) -> gemm_mfma -> gather2

typedef _Float16 f16;
typedef _Float16 f16x2 __attribute__((ext_vector_type(2)));
typedef _Float16 f16x4 __attribute__((ext_vector_type(4)));
typedef _Float16 f16x8 __attribute__((ext_vector_type(8)));
typedef float    f32x4 __attribute__((ext_vector_type(4)));

constexpr int NN   = 100000;
constexpr int NR   = NN * 2;     // (node, relation) segments
constexpr int NB   = 512;        // coarse buckets
constexpr int BSH  = 9;          // bucket = seg >> BSH (512 segs/bucket)
constexpr int CHUNK = 8192;      // edges per block in bucketA/B

__global__ void zero_small(int* __restrict__ gcnt) {
  int t = threadIdx.x;
  if (t < NB) gcnt[t] = 0;
}

__global__ void bucketA(const int* __restrict__ dst, const int* __restrict__ et,
                        int* __restrict__ gcnt, int E) {
  __shared__ int h[NB];
  int t = threadIdx.x;
  for (int b = t; b < NB; b += 256) h[b] = 0;
  __syncthreads();
  int lo = blockIdx.x * CHUNK, hi = min(E, lo + CHUNK);
  for (int e = lo + t; e < hi; e += 256)
    atomicAdd(&h[(dst[e] * 2 + et[e]) >> BSH], 1);
  __syncthreads();
  for (int b = t; b < NB; b += 256) {
    int c = h[b];
    if (c) atomicAdd(&gcnt[b], c);
  }
}

__global__ void bscan(const int* __restrict__ gcnt, int* __restrict__ bstart,
                      int* __restrict__ gbase) {  // 1 block, 512 threads
  __shared__ int s[NB];
  int t = threadIdx.x;
  int v = gcnt[t];
  s[t] = v;
  __syncthreads();
  #pragma unroll
  for (int o = 1; o < NB; o <<= 1) {
    int u = (t >= o) ? s[t - o] : 0;
    __syncthreads();
    s[t] += u;
    __syncthreads();
  }
  bstart[t] = s[t] - v;
  gbase[t]  = s[t] - v;
  if (t == NB - 1) bstart[NB] = s[t];
}

__global__ void bucketB(const int* __restrict__ src, const int* __restrict__ dst,
                        const int* __restrict__ et, int* __restrict__ gbase,
                        int2* __restrict__ ebuf, int E) {
  __shared__ int h[NB], base[NB];
  int t = threadIdx.x;
  for (int b = t; b < NB; b += 256) h[b] = 0;
  __syncthreads();
  int lo = blockIdx.x * CHUNK, hi = min(E, lo + CHUNK);
  for (int e = lo + t; e < hi; e += 256)
    atomicAdd(&h[(dst[e] * 2 + et[e]) >> BSH], 1);
  __syncthreads();
  for (int b = t; b < NB; b += 256) {
    int c = h[b];
    base[b] = c ? atomicAdd(&gbase[b], c) : 0;
    h[b] = 0;
  }
  __syncthreads();
  for (int e = lo + t; e < hi; e += 256) {
    int seg = dst[e] * 2 + et[e];
    int b = seg >> BSH;
    int r = atomicAdd(&h[b], 1);
    ebuf[base[b] + r] = make_int2(src[e], seg);
  }
}

// One block per bucket: build CSR off for its 512 segs + dense srcs scatter.
__global__ void bucketC(const int2* __restrict__ ebuf, const int* __restrict__ bstart,
                        int* __restrict__ off, int* __restrict__ srcs) {
  __shared__ int sh[NB], soff[NB], cnt[NB], tmp[256];
  int b = blockIdx.x, t = threadIdx.x;
  int lo = bstart[b], hi = bstart[b + 1];
  for (int s0 = t; s0 < NB; s0 += 256) { sh[s0] = 0; cnt[s0] = 0; }
  __syncthreads();
  for (int e = lo + t; e < hi; e += 256)
    atomicAdd(&sh[ebuf[e].y - (b << BSH)], 1);
  __syncthreads();
  int a0 = sh[2 * t], a1 = sh[2 * t + 1];
  tmp[t] = a0 + a1;
  __syncthreads();
  #pragma unroll
  for (int o = 1; o < 256; o <<= 1) {
    int u = (t >= o) ? tmp[t - o] : 0;
    __syncthreads();
    tmp[t] += u;
    __syncthreads();
  }
  int ex = tmp[t] - (a0 + a1);
  soff[2 * t] = ex;
  soff[2 * t + 1] = ex + a0;
  __syncthreads();
  int g0 = (b << BSH) + 2 * t;
  if (g0 <= NR)     off[g0]     = lo + soff[2 * t];
  if (g0 + 1 <= NR) off[g0 + 1] = lo + soff[2 * t + 1];
  for (int e = lo + t; e < hi; e += 256) {
    int2 p = ebuf[e];
    int s = p.y - (b << BSH);
    int r = atomicAdd(&cnt[s], 1);
    srcs[lo + soff[s] + r] = p.x;
  }
}

__global__ void cvt_x(const float4* __restrict__ xf, f16* __restrict__ xh, int n4) {
  int i = blockIdx.x * blockDim.x + threadIdx.x;
  if (i >= n4) return;
  float4 v = xf[i];
  f16x4 h;
  h.x = (f16)v.x; h.y = (f16)v.y; h.z = (f16)v.z; h.w = (f16)v.w;
  *(f16x4*)(xh + (size_t)i * 4) = h;
}

// k-step-major repack: w1t[ks][n][ki] = f16(W[ks*32+ki][n]).
__global__ void cvt_w(const float* __restrict__ w1s, const float* __restrict__ w1r,
                      f16* __restrict__ w1t) {
  int id = blockIdx.x * blockDim.x + threadIdx.x;
  if (id >= 12 * 256 * 32) return;
  int ks = id >> 13, rem = id & 8191;
  int n = rem >> 5, ki = rem & 31;
  int k = ks * 32 + ki;
  float v = (k < 128) ? w1s[k * 256 + n] : w1r[(k - 128) * 256 + n];
  w1t[id] = (f16)v;
}

// One wave per node; lane l owns cols 2l,2l+1; unroll x4 for outstanding loads.
__global__ void aggregate(const f16* __restrict__ xh, const int* __restrict__ off,
                          const int* __restrict__ srcs, f16* __restrict__ aggh) {
  int w = (blockIdx.x * blockDim.x + threadIdx.x) >> 6;
  if (w >= NN) return;
  int lane = threadIdx.x & 63;
  int e0 = off[2 * w];
  int e1 = off[2 * w + 1];
  int e2 = off[2 * w + 2];
  float a0 = 0.f, a1 = 0.f, c0 = 0.f, c1 = 0.f;
  int e = e0;
  for (; e + 3 < e1; e += 4) {
    f16x2 v0 = *(const f16x2*)(xh + (long)srcs[e] * 128 + lane * 2);
    f16x2 v1 = *(const f16x2*)(xh + (long)srcs[e + 1] * 128 + lane * 2);
    f16x2 v2 = *(const f16x2*)(xh + (long)srcs[e + 2] * 128 + lane * 2);
    f16x2 v3 = *(const f16x2*)(xh + (long)srcs[e + 3] * 128 + lane * 2);
    a0 += (float)v0.x + (float)v1.x + (float)v2.x + (float)v3.x;
    a1 += (float)v0.y + (float)v1.y + (float)v2.y + (float)v3.y;
  }
  for (; e < e1; ++e) {
    f16x2 v = *(const f16x2*)(xh + (long)srcs[e] * 128 + lane * 2);
    a0 += (float)v.x; a1 += (float)v.y;
  }
  e = e1;
  for (; e + 3 < e2; e += 4) {
    f16x2 v0 = *(const f16x2*)(xh + (long)srcs[e] * 128 + lane * 2);
    f16x2 v1 = *(const f16x2*)(xh + (long)srcs[e + 1] * 128 + lane * 2);
    f16x2 v2 = *(const f16x2*)(xh + (long)srcs[e + 2] * 128 + lane * 2);
    f16x2 v3 = *(const f16x2*)(xh + (long)srcs[e + 3] * 128 + lane * 2);
    c0 += (float)v0.x + (float)v1.x + (float)v2.x + (float)v3.x;
    c1 += (float)v0.y + (float)v1.y + (float)v2.y + (float)v3.y;
  }
  for (; e < e2; ++e) {
    f16x2 v = *(const f16x2*)(xh + (long)srcs[e] * 128 + lane * 2);
    c0 += (float)v.x; c1 += (float)v.y;
  }
  f16* row = aggh + (long)w * 256;
  f16x2 o0; o0.x = (f16)a0; o0.y = (f16)a1;
  f16x2 o1; o1.x = (f16)c0; o1.y = (f16)c1;
  *(f16x2*)(row + lane * 2) = o0;
  *(f16x2*)(row + 128 + lane * 2) = o1;
}

// Fused layer-1 GEMM (f16 MFMA) + layer-2 transform epilogue. Barrier-free:
// A and B fragments loaded straight from global (A: 16 rows x 64B = full
// lines per quad-set; B: w1t 192KB L2-resident). Block 256 thr = 4 waves;
// wave wv covers rows [blk*64, +64) x cols [wv*64, +64): acc 4x4 f32x4 = 64.
// Fragment layouts (m89/m120-verified): A: m=lane&15, k=quad*8+j;
// B: n=lane&15, k=quad*8+j; C/D: col=lane&15, row=quad*4+reg.
__global__ __launch_bounds__(256) void gemm_mfma(
    const f16* __restrict__ xh, const f16* __restrict__ aggh,
    const f16* __restrict__ w1t,
    const float* __restrict__ b1, const float* __restrict__ w2s,
    const float* __restrict__ w2r, const float* __restrict__ b2,
    float* __restrict__ z2, float* __restrict__ out) {
  __shared__ float zbuf[4][64][6];
  const int t = threadIdx.x;
  const int lane = t & 63, wv = t >> 6;
  const int ml = lane & 15, quad = lane >> 4;
  const long rowBase = (long)blockIdx.x * 64;

  // clamped rows for the 4 m-tiles (tail block reads row NN-1, write-masked)
  long rowc[4];
  #pragma unroll
  for (int mt = 0; mt < 4; ++mt) {
    long r = rowBase + mt * 16 + ml;
    rowc[mt] = r < NN ? r : (NN - 1);
  }
  // B lane offsets (halfs), invariant across ks
  const f16* bbase = w1t + (long)(wv * 64 + ml) * 32 + quad * 8;

  f32x4 acc[4][4];
  #pragma unroll
  for (int mt = 0; mt < 4; ++mt)
    #pragma unroll
    for (int nt = 0; nt < 4; ++nt) acc[mt][nt] = (f32x4)(0.f);

  #pragma unroll
  for (int ks = 0; ks < 12; ++ks) {
    f16x8 af[4], bf[4];
    #pragma unroll
    for (int mt = 0; mt < 4; ++mt) {
      const f16* ap = (ks < 4)
          ? (xh + rowc[mt] * 128 + ks * 32 + quad * 8)
          : (aggh + rowc[mt] * 256 + (ks - 4) * 32 + quad * 8);
      af[mt] = *(const f16x8*)ap;
    }
    #pragma unroll
    for (int nt = 0; nt < 4; ++nt)
      bf[nt] = *(const f16x8*)(bbase + (long)ks * 8192 + nt * 16 * 32);
    #pragma unroll
    for (int mt = 0; mt < 4; ++mt)
      #pragma unroll
      for (int nt = 0; nt < 4; ++nt)
        acc[mt][nt] = __builtin_amdgcn_mfma_f32_16x16x32_f16(af[mt], bf[nt],
                                                             acc[mt][nt], 0, 0, 0);
  }

  // Epilogue: h = relu(acc + b1[col]); 6 dots over this wave's 64 cols;
  // reduce over the 16 ml-lanes; accumulate partials into zbuf[wv].
  #pragma unroll
  for (int mt = 0; mt < 4; ++mt) {
    float z[4][6];
    #pragma unroll
    for (int rr = 0; rr < 4; ++rr)
      #pragma unroll
      for (int p = 0; p < 6; ++p) z[rr][p] = 0.f;
    #pragma unroll
    for (int nt = 0; nt < 4; ++nt) {
      int col = wv * 64 + nt * 16 + ml;
      float bb = b1[col];
      float wA = w2r[col * 2 + 0];
      float wB = w2r[col * 2 + 1];
      float wC = w2r[512 + col * 2 + 0];
      float wD = w2r[512 + col * 2 + 1];
      float wE = w2s[col * 2 + 0];
      float wF = w2s[col * 2 + 1];
      #pragma unroll
      for (int rr = 0; rr < 4; ++rr) {
        float h = acc[mt][nt][rr] + bb;
        h = h > 0.f ? h : 0.f;
        z[rr][0] = fmaf(h, wA, z[rr][0]);
        z[rr][1] = fmaf(h, wB, z[rr][1]);
        z[rr][2] = fmaf(h, wC, z[rr][2]);
        z[rr][3] = fmaf(h, wD, z[rr][3]);
        z[rr][4] = fmaf(h, wE, z[rr][4]);
        z[rr][5] = fmaf(h, wF, z[rr][5]);
      }
    }
    #pragma unroll
    for (int rr = 0; rr < 4; ++rr)
      #pragma unroll
      for (int p = 0; p < 6; ++p) {
        float v = z[rr][p];
        v += __shfl_xor(v, 1);
        v += __shfl_xor(v, 2);
        v += __shfl_xor(v, 4);
        v += __shfl_xor(v, 8);
        if (ml == 0) zbuf[wv][mt * 16 + quad * 4 + rr][p] = v;
      }
  }
  __syncthreads();
  for (int i = t; i < 384; i += 256) {
    int r = i / 6, p = i % 6;
    long grow = rowBase + r;
    if (grow < NN) {
      float v = zbuf[0][r][p] + zbuf[1][r][p] + zbuf[2][r][p] + zbuf[3][r][p];
      if (p < 4) z2[grow * 4 + p] = v;
      else       out[grow * 2 + (p - 4)] = v + b2[p - 4];
    }
  }
}

// 4 lanes per node: lane sub handles every-4th edge; reduce over sub.
__global__ void gather2(const float* __restrict__ z2, const int* __restrict__ off,
                        const int* __restrict__ srcs, float* __restrict__ out) {
  int tid = blockIdx.x * blockDim.x + threadIdx.x;
  int n = tid >> 2;
  if (n >= NN) return;
  int sub = tid & 3;
  int e0 = off[2 * n];
  int e1 = off[2 * n + 1];
  int e2 = off[2 * n + 2];
  float o0 = 0.f, o1 = 0.f;
  for (int e = e0 + sub; e < e1; e += 4) {
    float2 v = *(const float2*)(z2 + (long)srcs[e] * 4);
    o0 += v.x; o1 += v.y;
  }
  for (int e = e1 + sub; e < e2; e += 4) {
    float2 v = *(const float2*)(z2 + (long)srcs[e] * 4 + 2);
    o0 += v.x; o1 += v.y;
  }
  o0 += __shfl_xor(o0, 1); o1 += __shfl_xor(o1, 1);
  o0 += __shfl_xor(o0, 2); o1 += __shfl_xor(o1, 2);
  if (sub == 0) {
    out[n * 2 + 0] += o0;
    out[n * 2 + 1] += o1;
  }
}

extern "C" void kernel_launch(void* const* d_in, const int* in_sizes, int n_in,
                              void* d_out, int out_size, void* d_ws, size_t ws_size,
                              hipStream_t stream) {
  const float* x   = (const float*)d_in[0];
  const int*   ei  = (const int*)d_in[1];
  const int*   et  = (const int*)d_in[2];
  const float* w1s = (const float*)d_in[3];
  const float* w1r = (const float*)d_in[4];
  const float* b1  = (const float*)d_in[5];
  const float* w2s = (const float*)d_in[6];
  const float* w2r = (const float*)d_in[7];
  const float* b2  = (const float*)d_in[8];
  float* out = (float*)d_out;
  const int E = in_sizes[2];
  const int* src = ei;
  const int* dst = ei + E;

  f16*   aggh = (f16*)d_ws;                      // NN*256 f16   (51.2 MB)
  f16*   xh   = aggh + (size_t)NN * 256;         // NN*128 f16   (25.6 MB)
  f16*   w1t  = xh + (size_t)NN * 128;           // 12*256*32 f16 (0.2 MB)
  float* z2   = (float*)(w1t + 12 * 256 * 32);   // NN*4 f32     (1.6 MB)
  int2*  ebuf = (int2*)(z2 + (size_t)NN * 4);    // E int2       (12.8 MB)
  int*   srcs = (int*)(ebuf + E);                // E int        (6.4 MB)
  int*   off  = srcs + E;                        // NR+1 int     (0.8 MB)
  int*   gcnt = off + NR + 1;                    // NB int
  int*   bstart = gcnt + NB;                     // NB+1 int
  int*   gbase  = bstart + NB + 1;               // NB int

  int nblk = (E + CHUNK - 1) / CHUNK;
  zero_small<<<1, 512, 0, stream>>>(gcnt);
  bucketA<<<nblk, 256, 0, stream>>>(dst, et, gcnt, E);
  bscan<<<1, 512, 0, stream>>>(gcnt, bstart, gbase);
  bucketB<<<nblk, 256, 0, stream>>>(src, dst, et, gbase, ebuf, E);
  bucketC<<<NB, 256, 0, stream>>>(ebuf, bstart, off, srcs);

  int n4 = NN * 128 / 4;
  cvt_x<<<(n4 + 255) / 256, 256, 0, stream>>>((const float4*)x, xh, n4);
  cvt_w<<<(12 * 256 * 32 + 255) / 256, 256, 0, stream>>>(w1s, w1r, w1t);

  aggregate<<<(NN * 64 + 255) / 256, 256, 0, stream>>>(xh, off, srcs, aggh);

  gemm_mfma<<<(NN + 63) / 64, 256, 0, stream>>>(xh, aggh, w1t, b1, w2s, w2r, b2,
                                                z2, out);

  gather2<<<(NN * 4 + 255) / 256, 256, 0, stream>>>(z2, off, srcs, out);
}